// Round 5
// baseline (2622.333 us; speedup 1.0000x reference)
//
#include <hip/hip_runtime.h>
#include <math.h>

#define SEQ   2048
#define BATCH 64
#define IN    256
#define HID   256

typedef _Float16 hf2 __attribute__((ext_vector_type(2)));
typedef _Float16 hf8 __attribute__((ext_vector_type(8)));
typedef float    f32x4 __attribute__((ext_vector_type(4)));

static __device__ __forceinline__ float fast_sigmoid(float x) {
    return __builtin_amdgcn_rcpf(1.0f + __expf(-x));
}

static __device__ __forceinline__ float fast_tanh(float x) {
    const float e = __expf(-2.0f * fabsf(x));
    const float t = (1.0f - e) * __builtin_amdgcn_rcpf(1.0f + e);
    return copysignf(t, x);
}

// ---------------------------------------------------------------------------
// Kernel 0: Wz,Wh fp32 -> W16 [512][256] fp16 (rows 0-255 = Wz, 256-511 = Wh)
// ---------------------------------------------------------------------------
__global__ __launch_bounds__(256) void w16_kernel(
    const float* __restrict__ Wz, const float* __restrict__ Wh,
    _Float16* __restrict__ W16)
{
    const int idx = blockIdx.x * 256 + threadIdx.x;
    const int row = idx >> 8;
    const int col = idx & 255;
    const float v = (row < 256) ? Wz[row * 256 + col] : Wh[(row - 256) * 256 + col];
    W16[idx] = (_Float16)v;
}

// ---------------------------------------------------------------------------
// Kernel A: input projections via mfma_f32_16x16x32_f16 (validated R4).
// xz+bz+cz -> xz16 (fp16, d_ws); xh+bh+ch -> d_out fp32 (consumed by rec).
// ---------------------------------------------------------------------------
__global__ __launch_bounds__(256) void proj_mfma_kernel(
    const float* __restrict__ x,
    const _Float16* __restrict__ W16,
    const float* __restrict__ bz, const float* __restrict__ cz,
    const float* __restrict__ bh, const float* __restrict__ ch,
    _Float16* __restrict__ xz16,
    float* __restrict__ xh_out)
{
    const int tid  = threadIdx.x;
    const int lane = tid & 63;
    const int w    = tid >> 6;
    const int m0   = blockIdx.x * 16;
    const int col0 = w * 128;

    const int r = lane & 15;
    const int g = lane >> 4;

    f32x4 acc[8] = {f32x4{0,0,0,0}, f32x4{0,0,0,0}, f32x4{0,0,0,0}, f32x4{0,0,0,0},
                    f32x4{0,0,0,0}, f32x4{0,0,0,0}, f32x4{0,0,0,0}, f32x4{0,0,0,0}};

    const float*    xrow  = x   + (size_t)(m0 + r) * IN + g * 8;
    const _Float16* wbase = W16 + (size_t)(col0 + r) * IN + g * 8;

#pragma unroll
    for (int kt = 0; kt < 8; ++kt) {
        const float4 xa = *reinterpret_cast<const float4*>(xrow + kt * 32);
        const float4 xb = *reinterpret_cast<const float4*>(xrow + kt * 32 + 4);
        hf8 a;
        a[0] = (_Float16)xa.x; a[1] = (_Float16)xa.y;
        a[2] = (_Float16)xa.z; a[3] = (_Float16)xa.w;
        a[4] = (_Float16)xb.x; a[5] = (_Float16)xb.y;
        a[6] = (_Float16)xb.z; a[7] = (_Float16)xb.w;
#pragma unroll
        for (int t = 0; t < 8; ++t) {
            const hf8 bfrag = *reinterpret_cast<const hf8*>(
                wbase + (size_t)t * 16 * IN + kt * 32);
            acc[t] = __builtin_amdgcn_mfma_f32_16x16x32_f16(a, bfrag, acc[t], 0, 0, 0);
        }
    }

    if (w < 2) {
#pragma unroll
        for (int t = 0; t < 8; ++t) {
            const int c = col0 + t * 16 + r;
            const float bsum = bz[c] + cz[c];
#pragma unroll
            for (int reg = 0; reg < 4; ++reg) {
                const int m = m0 + 4 * g + reg;
                xz16[(size_t)m * HID + c] = (_Float16)(acc[t][reg] + bsum);
            }
        }
    } else {
#pragma unroll
        for (int t = 0; t < 8; ++t) {
            const int c = col0 - 256 + t * 16 + r;
            const float bsum = bh[c] + ch[c];
#pragma unroll
            for (int reg = 0; reg < 4; ++reg) {
                const int m = m0 + 4 * g + reg;
                xh_out[(size_t)m * HID + c] = acc[t][reg] + bsum;
            }
        }
    }
}

// ---------------------------------------------------------------------------
// Kernel B: MFMA recurrence. 4 WGs x 16 batches, 512 thr (8 waves).
// Wave w owns cols [32w, 32w+32) = col-tiles {2w, 2w+1}; for each tile it
// computes BOTH the z-preact (Uz) and h~-preact (Uh) -> z and h~ for a given
// (batch,o) land in the SAME lane & reg. U register-resident as fp16
// B-fragments (128 VGPRs). h operand: fp16 in LDS [2][16][256], XOR-swizzled
// at 16B-block granularity (blk^(row&7)) -> A-frag ds_read_b128 is <=2-way
// (free). h_prev: exact fp32 in the owning lane's registers (C/D position is
// step-invariant). xz16 is the MFMA C-initializer (no epilogue add); xz/xh
// for t+1 prefetched during step t. One barrier/step.
// Fragment maps (R4-validated): A lane l: row=l&15, k=8*(l>>4)+j;
// B lane l: col=l&15, k=8*(l>>4)+j; C/D lane l: col=l&15, row=4*(l>>4)+reg.
// ---------------------------------------------------------------------------
__global__ __launch_bounds__(512) void rec_mfma_kernel(
    const float* __restrict__ hidden0,
    const float* __restrict__ Uz,
    const float* __restrict__ Uh,
    const _Float16* __restrict__ xz16,
    float* __restrict__ out,
    float* __restrict__ h_final)
{
    const int wg  = blockIdx.x;        // 0..3
    const int b0  = wg * 16;           // batch base
    const int tid = threadIdx.x;
    const int w   = tid >> 6;          // wave 0..7
    const int lane = tid & 63;
    const int r   = lane & 15;
    const int g   = lane >> 4;
    const int c0  = 32 * w + r;        // col in tile 0
    const int c1  = 32 * w + 16 + r;   // col in tile 1

    __shared__ __align__(16) _Float16 hbuf[2][16 * 256];

    // ---- B-fragments: lane l holds U[col][kt*32 + 8g .. +7] as fp16 ----
    hf8 buz0[8], buz1[8], buh0[8], buh1[8];
#pragma unroll
    for (int kt = 0; kt < 8; ++kt) {
        const size_t ko = (size_t)kt * 32 + 8 * g;
        float4 v0, v1;
        hf8 f;
        v0 = *reinterpret_cast<const float4*>(Uz + (size_t)c0 * HID + ko);
        v1 = *reinterpret_cast<const float4*>(Uz + (size_t)c0 * HID + ko + 4);
        f[0]=(_Float16)v0.x; f[1]=(_Float16)v0.y; f[2]=(_Float16)v0.z; f[3]=(_Float16)v0.w;
        f[4]=(_Float16)v1.x; f[5]=(_Float16)v1.y; f[6]=(_Float16)v1.z; f[7]=(_Float16)v1.w;
        buz0[kt] = f;
        v0 = *reinterpret_cast<const float4*>(Uz + (size_t)c1 * HID + ko);
        v1 = *reinterpret_cast<const float4*>(Uz + (size_t)c1 * HID + ko + 4);
        f[0]=(_Float16)v0.x; f[1]=(_Float16)v0.y; f[2]=(_Float16)v0.z; f[3]=(_Float16)v0.w;
        f[4]=(_Float16)v1.x; f[5]=(_Float16)v1.y; f[6]=(_Float16)v1.z; f[7]=(_Float16)v1.w;
        buz1[kt] = f;
        v0 = *reinterpret_cast<const float4*>(Uh + (size_t)c0 * HID + ko);
        v1 = *reinterpret_cast<const float4*>(Uh + (size_t)c0 * HID + ko + 4);
        f[0]=(_Float16)v0.x; f[1]=(_Float16)v0.y; f[2]=(_Float16)v0.z; f[3]=(_Float16)v0.w;
        f[4]=(_Float16)v1.x; f[5]=(_Float16)v1.y; f[6]=(_Float16)v1.z; f[7]=(_Float16)v1.w;
        buh0[kt] = f;
        v0 = *reinterpret_cast<const float4*>(Uh + (size_t)c1 * HID + ko);
        v1 = *reinterpret_cast<const float4*>(Uh + (size_t)c1 * HID + ko + 4);
        f[0]=(_Float16)v0.x; f[1]=(_Float16)v0.y; f[2]=(_Float16)v0.z; f[3]=(_Float16)v0.w;
        f[4]=(_Float16)v1.x; f[5]=(_Float16)v1.y; f[6]=(_Float16)v1.z; f[7]=(_Float16)v1.w;
        buh1[kt] = f;
    }

    // ---- init LDS h (swizzled) + fp32 h_prev registers ----
    {
        const int bb = tid >> 5;                 // 0..15
        const int kb = (tid & 31) * 8;           // 0,8,..248 (one 16B block)
        const float4 v0 = *reinterpret_cast<const float4*>(
            hidden0 + (size_t)(b0 + bb) * HID + kb);
        const float4 v1 = *reinterpret_cast<const float4*>(
            hidden0 + (size_t)(b0 + bb) * HID + kb + 4);
        hf8 f;
        f[0]=(_Float16)v0.x; f[1]=(_Float16)v0.y; f[2]=(_Float16)v0.z; f[3]=(_Float16)v0.w;
        f[4]=(_Float16)v1.x; f[5]=(_Float16)v1.y; f[6]=(_Float16)v1.z; f[7]=(_Float16)v1.w;
        *reinterpret_cast<hf8*>(
            &hbuf[0][bb * 256 + (((kb >> 3) ^ (bb & 7)) << 3)]) = f;
    }
    float hp0[4], hp1[4];
#pragma unroll
    for (int reg = 0; reg < 4; ++reg) {
        hp0[reg] = hidden0[(size_t)(b0 + 4 * g + reg) * HID + c0];
        hp1[reg] = hidden0[(size_t)(b0 + 4 * g + reg) * HID + c1];
    }

    // ---- prefetch xz/xh for t=0 ----
    float pz0[4], pz1[4], ph0[4], ph1[4];
#pragma unroll
    for (int reg = 0; reg < 4; ++reg) {
        const size_t row = (size_t)(b0 + 4 * g + reg) * HID;
        pz0[reg] = (float)xz16[row + c0];
        pz1[reg] = (float)xz16[row + c1];
        ph0[reg] = out[row + c0];
        ph1[reg] = out[row + c1];
    }
    __syncthreads();

    const int rx = r & 7;
    const int rowoff = r * 256;

#define REC_STEP(CUR, NXT, T)                                                  \
    {                                                                          \
        /* A-fragments from hbuf[CUR] (swizzled blocks) */                     \
        hf8 a[8];                                                              \
        _Pragma("unroll")                                                      \
        for (int kt = 0; kt < 8; ++kt) {                                       \
            a[kt] = *reinterpret_cast<const hf8*>(                             \
                &hbuf[CUR][rowoff + ((((kt * 4) + g) ^ rx) << 3)]);            \
        }                                                                      \
        /* acc init = staged xz / xh (C-operand), then prefetch T+1 */         \
        f32x4 az0{pz0[0], pz0[1], pz0[2], pz0[3]};                             \
        f32x4 az1{pz1[0], pz1[1], pz1[2], pz1[3]};                             \
        f32x4 ah0{ph0[0], ph0[1], ph0[2], ph0[3]};                             \
        f32x4 ah1{ph1[0], ph1[1], ph1[2], ph1[3]};                             \
        const size_t nb = ((size_t)(T + 1) * BATCH + b0 + 4 * g) * HID;        \
        _Pragma("unroll")                                                      \
        for (int reg = 0; reg < 4; ++reg) {                                    \
            pz0[reg] = (float)xz16[nb + (size_t)reg * HID + c0];               \
            pz1[reg] = (float)xz16[nb + (size_t)reg * HID + c1];               \
            ph0[reg] = out[nb + (size_t)reg * HID + c0];                       \
            ph1[reg] = out[nb + (size_t)reg * HID + c1];                       \
        }                                                                      \
        _Pragma("unroll")                                                      \
        for (int kt = 0; kt < 8; ++kt) {                                       \
            az0 = __builtin_amdgcn_mfma_f32_16x16x32_f16(a[kt], buz0[kt], az0, 0, 0, 0); \
            az1 = __builtin_amdgcn_mfma_f32_16x16x32_f16(a[kt], buz1[kt], az1, 0, 0, 0); \
            ah0 = __builtin_amdgcn_mfma_f32_16x16x32_f16(a[kt], buh0[kt], ah0, 0, 0, 0); \
            ah1 = __builtin_amdgcn_mfma_f32_16x16x32_f16(a[kt], buh1[kt], ah1, 0, 0, 0); \
        }                                                                      \
        /* epilogue: z, h~, h_new; store out + swizzled LDS fp16 */            \
        const size_t ob = ((size_t)(T) * BATCH + b0 + 4 * g) * HID;            \
        _Pragma("unroll")                                                      \
        for (int reg = 0; reg < 4; ++reg) {                                    \
            const int bb = 4 * g + reg;                                        \
            const float z0v = fast_sigmoid(az0[reg]);                          \
            const float t0v = fast_tanh(ah0[reg]);                             \
            const float hn0 = fmaf(z0v, t0v - hp0[reg], hp0[reg]);             \
            hp0[reg] = hn0;                                                    \
            out[ob + (size_t)reg * HID + c0] = hn0;                            \
            hbuf[NXT][bb * 256 + ((((c0 >> 3)) ^ (bb & 7)) << 3) + (c0 & 7)] = \
                (_Float16)hn0;                                                 \
            const float z1v = fast_sigmoid(az1[reg]);                          \
            const float t1v = fast_tanh(ah1[reg]);                             \
            const float hn1 = fmaf(z1v, t1v - hp1[reg], hp1[reg]);             \
            hp1[reg] = hn1;                                                    \
            out[ob + (size_t)reg * HID + c1] = hn1;                            \
            hbuf[NXT][bb * 256 + ((((c1 >> 3)) ^ (bb & 7)) << 3) + (c1 & 7)] = \
                (_Float16)hn1;                                                 \
        }                                                                      \
        __syncthreads();                                                       \
    }

    for (int t = 0; t < SEQ; t += 2) {
        REC_STEP(0, 1, t)
        REC_STEP(1, 0, t + 1)
    }
#undef REC_STEP

#pragma unroll
    for (int reg = 0; reg < 4; ++reg) {
        h_final[(size_t)(b0 + 4 * g + reg) * HID + c0] = hp0[reg];
        h_final[(size_t)(b0 + 4 * g + reg) * HID + c1] = hp1[reg];
    }
}

extern "C" void kernel_launch(void* const* d_in, const int* in_sizes, int n_in,
                              void* d_out, int out_size, void* d_ws, size_t ws_size,
                              hipStream_t stream) {
    const float* x      = (const float*)d_in[0];
    const float* hidden = (const float*)d_in[1];
    const float* Wz     = (const float*)d_in[2];
    const float* bz     = (const float*)d_in[3];
    const float* Uz     = (const float*)d_in[4];
    const float* cz     = (const float*)d_in[5];
    const float* Wh     = (const float*)d_in[6];
    const float* bh     = (const float*)d_in[7];
    const float* Uh     = (const float*)d_in[8];
    const float* ch     = (const float*)d_in[9];

    float* out     = (float*)d_out;                        // [SEQ*BATCH*HID]
    float* h_final = out + (size_t)SEQ * BATCH * HID;      // [BATCH*HID]

    _Float16* xz16 = (_Float16*)d_ws;                               // 64 MiB
    _Float16* W16  = (_Float16*)((char*)d_ws + ((size_t)64 << 20)); // 256 KiB

    w16_kernel<<<512, 256, 0, stream>>>(Wz, Wh, W16);

    proj_mfma_kernel<<<(SEQ * BATCH) / 16, 256, 0, stream>>>(
        x, W16, bz, cz, bh, ch, xz16, out);

    rec_mfma_kernel<<<4, 512, 0, stream>>>(
        hidden, Uz, Uh, xz16, out, h_final);
}